// Round 4
// baseline (859.206 us; speedup 1.0000x reference)
//
#include <hip/hip_runtime.h>
#include <hip/hip_bf16.h>
#include <math.h>

// Problem constants (Qwen3 MoE block)
#define T_TOK 2048
#define H_DIM 2048
#define NEXP  64
#define TOPK  8
#define I_DIM 768
#define CAPE  512
#define MTMAX 4     // CAPE/128
#define LDW   40    // LDS row stride in shorts (80B)
#define YROWS 24576 // compact-y row capacity (sum of ceil128(cnt))

typedef short bf16x8 __attribute__((ext_vector_type(8)));
typedef float f32x4  __attribute__((ext_vector_type(4)));

__device__ __forceinline__ unsigned short f2bf(float f) {
  unsigned u = __float_as_uint(f);
  u += 0x7fffu + ((u >> 16) & 1u);   // RNE
  return (unsigned short)(u >> 16);
}
__device__ __forceinline__ float bf2f(unsigned short b) {
  return __uint_as_float(((unsigned)b) << 16);
}
__device__ __forceinline__ unsigned pack2(float lo, float hi) {
  __hip_bfloat162 h = __float22bfloat162_rn(make_float2(lo, hi));  // v_cvt_pk_bf16_f32
  unsigned r; __builtin_memcpy(&r, &h, 4); return r;
}
// LDS-consistency barrier that does NOT drain vmcnt (keeps global prefetch in flight)
__device__ __forceinline__ void lds_barrier() {
  asm volatile("s_waitcnt lgkmcnt(0)" ::: "memory");
  __builtin_amdgcn_s_barrier();
  __builtin_amdgcn_sched_barrier(0);
}

// ---------------- K1: router logits + softmax-top8 + renorm ----------------
__global__ __launch_bounds__(256) void k_router(const float* __restrict__ x,
                                                const float* __restrict__ wr,
                                                int* __restrict__ topk_idx,
                                                float* __restrict__ topk_w) {
  const int lane = threadIdx.x & 63;
  const int t = blockIdx.x * 4 + (threadIdx.x >> 6);
  const float4* xr   = (const float4*)(x + (size_t)t * H_DIM);
  const float4* wrow = (const float4*)(wr + (size_t)lane * H_DIM);
  double acc = 0.0;                      // fp64: minimize top-k tie risk
  for (int i = 0; i < H_DIM / 4; ++i) {
    float4 a = xr[i], b = wrow[i];
    acc += (double)a.x * b.x; acc += (double)a.y * b.y;
    acc += (double)a.z * b.z; acc += (double)a.w * b.w;
  }
  float cur = (float)acc;
  float val[TOPK]; int idx[TOPK];
#pragma unroll
  for (int r = 0; r < TOPK; ++r) {
    float bv = cur; int bi = lane;
#pragma unroll
    for (int off = 32; off > 0; off >>= 1) {   // argmax, ties -> lower index
      float ov = __shfl_xor(bv, off);
      int   oi = __shfl_xor(bi, off);
      if (ov > bv || (ov == bv && oi < bi)) { bv = ov; bi = oi; }
    }
    val[r] = bv; idx[r] = bi;
    if (lane == bi) cur = -INFINITY;
  }
  float m = val[0], s = 0.f, w[TOPK];
#pragma unroll
  for (int r = 0; r < TOPK; ++r) { w[r] = expf(val[r] - m); s += w[r]; }
  if (lane < TOPK) {
    topk_idx[t * TOPK + lane] = idx[lane];
    topk_w [t * TOPK + lane] = w[lane] / s;
  }
}

// ---------------- K2: stable rank within expert + padded prefix ------------
__global__ __launch_bounds__(256) void k_rank(const int* __restrict__ topk_idx,
                                              int* __restrict__ pair_pos,
                                              int* __restrict__ slot_token,
                                              int* __restrict__ cnts,
                                              int* __restrict__ pstart) {
  __shared__ int s_run[64];
  __shared__ int s_whist[4][64];
  const int tid = threadIdx.x, lane = tid & 63, wv = tid >> 6;
  if (tid < 64) s_run[tid] = 0;
  for (int c = 0; c < 64; ++c) {
    const int p = c * 256 + tid;
    const int e = topk_idx[p];
    __syncthreads();
    s_whist[wv][lane] = 0;
    __syncthreads();
    unsigned long long m = ~0ull;
#pragma unroll
    for (int b = 0; b < 6; ++b) {
      unsigned long long bb = __ballot((e >> b) & 1);
      m &= ((e >> b) & 1) ? bb : ~bb;
    }
    const int rw = __popcll(m & ((1ull << lane) - 1ull));
    if (rw == 0) s_whist[wv][e] = __popcll(m);
    __syncthreads();
    int r = rw;
    for (int w2 = 0; w2 < wv; ++w2) r += s_whist[w2][e];
    const int pos = s_run[e] + r;
    pair_pos[p] = pos;
    if (pos < CAPE) slot_token[e * CAPE + pos] = p >> 3;
    __syncthreads();
    if (tid < 64)
      s_run[tid] += s_whist[0][tid] + s_whist[1][tid] + s_whist[2][tid] + s_whist[3][tid];
  }
  __syncthreads();
  if (tid < 64) cnts[tid] = s_run[tid];
  if (tid == 0) {
    int run = 0;
    for (int ee = 0; ee < 64; ++ee) {
      pstart[ee] = run;
      int c = s_run[ee]; if (c > CAPE) c = CAPE;
      run += (c + 127) & ~127;
    }
    pstart[64] = run;
  }
}

// ---------------- K3: mm1 = X @ {Wg|Wu} -> gbuf/ubuf (bf16) ----------------
// grid = E*MTMAX*12 (nti<6 -> gate cols, else up); block = 256 (4 waves 2x2),
// tile 128x128, wave tile 64x64. LDS dbuf, 1 raw barrier/step, reg prefetch.
__global__ __launch_bounds__(256, 3) void k_mm1(const float* __restrict__ x,
                                                const float* __restrict__ wg,
                                                const float* __restrict__ wu,
                                                const int* __restrict__ slot_token,
                                                const int* __restrict__ cnts,
                                                unsigned short* __restrict__ gbuf,
                                                unsigned short* __restrict__ ubuf) {
  const int NB = NEXP * MTMAX * 12;
  const int v = (blockIdx.x & 7) * (NB / 8) + (blockIdx.x >> 3);  // XCD chunk swizzle
  const int e = v / (MTMAX * 12);
  const int rem = v % (MTMAX * 12);
  const int mt = rem / 12, nti = rem % 12;

  int cnt = cnts[e]; cnt = cnt < CAPE ? cnt : CAPE;
  if (cnt <= 0 || mt * 128 >= cnt) return;
  const int m0 = mt << 7;
  const float* wsrc = (nti < 6) ? wg : wu;
  unsigned short* obuf = (nti < 6) ? gbuf : ubuf;
  const int ncol = (nti % 6) * 128;

  __shared__ __align__(16) short As[2][128 * LDW];   // 10 KiB each
  __shared__ __align__(16) short Bs[2][128 * LDW];

  const int tid = threadIdx.x;
  const int lane = tid & 63, wave = tid >> 6;
  const int wm = wave >> 1, wn = wave & 1;       // 2x2 waves, 64x64 tiles
  const int lr = lane & 15, lg = lane >> 4;

  // A staging: row = tid>>1 (0..127), half = tid&1 (16 consecutive k-floats)
  const int a_row = tid >> 1, a_half = tid & 1;
  // B staging: 2 tasks: kp = tid&15 (k-pair), nq = (tid>>4) + 16*s (col-quad)
  const int b_kp = tid & 15;
  const int b_nq0 = tid >> 4, b_nq1 = b_nq0 + 16;
  const size_t wbase = (size_t)e * H_DIM * I_DIM + (size_t)ncol;

  const int tok = (m0 + a_row < cnt) ? slot_token[e * CAPE + m0 + a_row] : 0;
  const float* xr = x + (size_t)tok * H_DIM + a_half * 16;
  const float* bp = wsrc + wbase + (size_t)(2 * b_kp) * I_DIM;

  f32x4 acc[4][4];
#pragma unroll
  for (int mi = 0; mi < 4; ++mi)
#pragma unroll
    for (int ni = 0; ni < 4; ++ni) acc[mi][ni] = (f32x4){0.f, 0.f, 0.f, 0.f};

  struct Tile { float4 a[4]; float4 b0[2]; float4 b1[2]; };
  Tile T;

  auto LOAD = [&](int kt) {
    const int k0 = kt * 32;
#pragma unroll
    for (int j = 0; j < 4; ++j) T.a[j] = *(const float4*)(xr + k0 + j * 4);
    const float* r0 = bp + (size_t)k0 * I_DIM;
    T.b0[0] = *(const float4*)(r0 + 4 * b_nq0);
    T.b0[1] = *(const float4*)(r0 + I_DIM + 4 * b_nq0);
    T.b1[0] = *(const float4*)(r0 + 4 * b_nq1);
    T.b1[1] = *(const float4*)(r0 + I_DIM + 4 * b_nq1);
  };
  auto STORE = [&](int b) {
    uint4 w0 = { pack2(T.a[0].x, T.a[0].y), pack2(T.a[0].z, T.a[0].w),
                 pack2(T.a[1].x, T.a[1].y), pack2(T.a[1].z, T.a[1].w) };
    uint4 w1 = { pack2(T.a[2].x, T.a[2].y), pack2(T.a[2].z, T.a[2].w),
                 pack2(T.a[3].x, T.a[3].y), pack2(T.a[3].z, T.a[3].w) };
    *(uint4*)(&As[b][a_row * LDW + a_half * 16])     = w0;
    *(uint4*)(&As[b][a_row * LDW + a_half * 16 + 8]) = w1;
    *(unsigned*)(&Bs[b][(4 * b_nq0 + 0) * LDW + 2 * b_kp]) = pack2(T.b0[0].x, T.b0[1].x);
    *(unsigned*)(&Bs[b][(4 * b_nq0 + 1) * LDW + 2 * b_kp]) = pack2(T.b0[0].y, T.b0[1].y);
    *(unsigned*)(&Bs[b][(4 * b_nq0 + 2) * LDW + 2 * b_kp]) = pack2(T.b0[0].z, T.b0[1].z);
    *(unsigned*)(&Bs[b][(4 * b_nq0 + 3) * LDW + 2 * b_kp]) = pack2(T.b0[0].w, T.b0[1].w);
    *(unsigned*)(&Bs[b][(4 * b_nq1 + 0) * LDW + 2 * b_kp]) = pack2(T.b1[0].x, T.b1[1].x);
    *(unsigned*)(&Bs[b][(4 * b_nq1 + 1) * LDW + 2 * b_kp]) = pack2(T.b1[0].y, T.b1[1].y);
    *(unsigned*)(&Bs[b][(4 * b_nq1 + 2) * LDW + 2 * b_kp]) = pack2(T.b1[0].z, T.b1[1].z);
    *(unsigned*)(&Bs[b][(4 * b_nq1 + 3) * LDW + 2 * b_kp]) = pack2(T.b1[0].w, T.b1[1].w);
  };
  auto COMPUTE = [&](int b) {
    bf16x8 af[4], bf[4];
#pragma unroll
    for (int mi = 0; mi < 4; ++mi)
      af[mi] = *(const bf16x8*)(&As[b][(wm * 64 + mi * 16 + lr) * LDW + lg * 8]);
#pragma unroll
    for (int ni = 0; ni < 4; ++ni)
      bf[ni] = *(const bf16x8*)(&Bs[b][(wn * 64 + ni * 16 + lr) * LDW + lg * 8]);
    __builtin_amdgcn_s_setprio(1);
#pragma unroll
    for (int mi = 0; mi < 4; ++mi)
#pragma unroll
      for (int ni = 0; ni < 4; ++ni)
        acc[mi][ni] = __builtin_amdgcn_mfma_f32_16x16x32_bf16(af[mi], bf[ni], acc[mi][ni], 0, 0, 0);
    __builtin_amdgcn_s_setprio(0);
  };

  const int NK = H_DIM / 32;   // 64, even
  LOAD(0); STORE(0); LOAD(1);
  lds_barrier();

#pragma unroll 1
  for (int t = 0; t + 2 < NK; t += 2) {
    COMPUTE(0); STORE(1); LOAD(t + 2);
    lds_barrier();
    COMPUTE(1); STORE(0); LOAD(t + 3);
    lds_barrier();
  }
  COMPUTE(0); STORE(1);
  lds_barrier();
  COMPUTE(1);

#pragma unroll
  for (int mi = 0; mi < 4; ++mi)
#pragma unroll
    for (int ni = 0; ni < 4; ++ni)
#pragma unroll
      for (int r = 0; r < 4; ++r) {
        const int row = m0 + wm * 64 + mi * 16 + lg * 4 + r;
        const int col = ncol + wn * 64 + ni * 16 + lr;
        obuf[(size_t)(e * CAPE + row) * I_DIM + col] = f2bf(acc[mi][ni][r]);
      }
}

// ---------------- K4: act = silu(g) * u, in-place into gbuf ----------------
__global__ __launch_bounds__(256) void k_act(unsigned short* __restrict__ gbuf,
                                             const unsigned short* __restrict__ ubuf,
                                             const int* __restrict__ cnts) {
  const int e = blockIdx.x >> 6;
  const int r0 = (blockIdx.x & 63) * 8;
  int cnt = cnts[e]; cnt = cnt < CAPE ? cnt : CAPE;
  const int lim = (cnt + 127) & ~127;
  if (r0 >= lim) return;
#pragma unroll
  for (int s = 0; s < 3; ++s) {
    const int c = threadIdx.x + 256 * s;
    const int row = r0 + c / 96;
    const int col = (c % 96) * 8;
    const size_t idx = (size_t)(e * CAPE + row) * I_DIM + col;
    bf16x8 g8 = *(const bf16x8*)(gbuf + idx);
    bf16x8 u8 = *(const bf16x8*)(ubuf + idx);
    bf16x8 o;
#pragma unroll
    for (int j = 0; j < 8; ++j) {
      const float g = bf2f((unsigned short)g8[j]);
      const float u = bf2f((unsigned short)u8[j]);
      o[j] = (short)f2bf((g / (1.f + __expf(-g))) * u);
    }
    *(bf16x8*)(gbuf + idx) = o;
  }
}

// ---------------- K5: down GEMM -> y (bf16, compact rows) ------------------
// grid = E*MTMAX*16; block = 256 (4 waves 2x2). Same pipeline as mm1.
__global__ __launch_bounds__(256, 3) void k_down(const unsigned short* __restrict__ act,
                                                 const float* __restrict__ wd,
                                                 const int* __restrict__ cnts,
                                                 const int* __restrict__ pstart,
                                                 unsigned short* __restrict__ y) {
  const int NB = NEXP * MTMAX * 16;
  const int v = (blockIdx.x & 7) * (NB / 8) + (blockIdx.x >> 3);
  const int e = v / (MTMAX * 16);
  const int rem = v % (MTMAX * 16);
  const int mt = rem / 16, nt = rem % 16;

  int cnt = cnts[e]; cnt = cnt < CAPE ? cnt : CAPE;
  if (cnt <= 0 || mt * 128 >= cnt) return;
  const int m0 = mt << 7;
  const int ybase = pstart[e];
  if (ybase + m0 + 128 > YROWS) return;   // never in practice

  __shared__ __align__(16) short As[2][128 * LDW];
  __shared__ __align__(16) short Bs[2][128 * LDW];

  const int tid = threadIdx.x;
  const int lane = tid & 63, wave = tid >> 6;
  const int wm = wave >> 1, wn = wave & 1;
  const int lr = lane & 15, lg = lane >> 4;

  const int a_row = tid >> 1, a_half = tid & 1;
  const int b_kp = tid & 15;
  const int b_nq0 = tid >> 4, b_nq1 = b_nq0 + 16;
  const size_t wbase = (size_t)e * I_DIM * H_DIM + (size_t)nt * 128;

  const unsigned short* ap = act + (size_t)(e * CAPE + m0 + a_row) * I_DIM + a_half * 16;
  const float* bp = wd + wbase + (size_t)(2 * b_kp) * H_DIM;

  f32x4 acc[4][4];
#pragma unroll
  for (int mi = 0; mi < 4; ++mi)
#pragma unroll
    for (int ni = 0; ni < 4; ++ni) acc[mi][ni] = (f32x4){0.f, 0.f, 0.f, 0.f};

  struct Tile { bf16x8 a[2]; float4 b0[2]; float4 b1[2]; };
  Tile T;

  auto LOAD = [&](int kt) {
    const int k0 = kt * 32;
    T.a[0] = *(const bf16x8*)(ap + k0);
    T.a[1] = *(const bf16x8*)(ap + k0 + 8);
    const float* r0 = bp + (size_t)k0 * H_DIM;
    T.b0[0] = *(const float4*)(r0 + 4 * b_nq0);
    T.b0[1] = *(const float4*)(r0 + H_DIM + 4 * b_nq0);
    T.b1[0] = *(const float4*)(r0 + 4 * b_nq1);
    T.b1[1] = *(const float4*)(r0 + H_DIM + 4 * b_nq1);
  };
  auto STORE = [&](int b) {
    *(bf16x8*)(&As[b][a_row * LDW + a_half * 16])     = T.a[0];
    *(bf16x8*)(&As[b][a_row * LDW + a_half * 16 + 8]) = T.a[1];
    *(unsigned*)(&Bs[b][(4 * b_nq0 + 0) * LDW + 2 * b_kp]) = pack2(T.b0[0].x, T.b0[1].x);
    *(unsigned*)(&Bs[b][(4 * b_nq0 + 1) * LDW + 2 * b_kp]) = pack2(T.b0[0].y, T.b0[1].y);
    *(unsigned*)(&Bs[b][(4 * b_nq0 + 2) * LDW + 2 * b_kp]) = pack2(T.b0[0].z, T.b0[1].z);
    *(unsigned*)(&Bs[b][(4 * b_nq0 + 3) * LDW + 2 * b_kp]) = pack2(T.b0[0].w, T.b0[1].w);
    *(unsigned*)(&Bs[b][(4 * b_nq1 + 0) * LDW + 2 * b_kp]) = pack2(T.b1[0].x, T.b1[1].x);
    *(unsigned*)(&Bs[b][(4 * b_nq1 + 1) * LDW + 2 * b_kp]) = pack2(T.b1[0].y, T.b1[1].y);
    *(unsigned*)(&Bs[b][(4 * b_nq1 + 2) * LDW + 2 * b_kp]) = pack2(T.b1[0].z, T.b1[1].z);
    *(unsigned*)(&Bs[b][(4 * b_nq1 + 3) * LDW + 2 * b_kp]) = pack2(T.b1[0].w, T.b1[1].w);
  };
  auto COMPUTE = [&](int b) {
    bf16x8 af[4], bf[4];
#pragma unroll
    for (int mi = 0; mi < 4; ++mi)
      af[mi] = *(const bf16x8*)(&As[b][(wm * 64 + mi * 16 + lr) * LDW + lg * 8]);
#pragma unroll
    for (int ni = 0; ni < 4; ++ni)
      bf[ni] = *(const bf16x8*)(&Bs[b][(wn * 64 + ni * 16 + lr) * LDW + lg * 8]);
    __builtin_amdgcn_s_setprio(1);
#pragma unroll
    for (int mi = 0; mi < 4; ++mi)
#pragma unroll
      for (int ni = 0; ni < 4; ++ni)
        acc[mi][ni] = __builtin_amdgcn_mfma_f32_16x16x32_bf16(af[mi], bf[ni], acc[mi][ni], 0, 0, 0);
    __builtin_amdgcn_s_setprio(0);
  };

  const int NK = I_DIM / 32;   // 24, even
  LOAD(0); STORE(0); LOAD(1);
  lds_barrier();

#pragma unroll 1
  for (int t = 0; t + 2 < NK; t += 2) {
    COMPUTE(0); STORE(1); LOAD(t + 2);
    lds_barrier();
    COMPUTE(1); STORE(0); LOAD(t + 3);
    lds_barrier();
  }
  COMPUTE(0); STORE(1);
  lds_barrier();
  COMPUTE(1);

#pragma unroll
  for (int mi = 0; mi < 4; ++mi)
#pragma unroll
    for (int ni = 0; ni < 4; ++ni)
#pragma unroll
      for (int r = 0; r < 4; ++r) {
        const int row = ybase + m0 + wm * 64 + mi * 16 + lg * 4 + r;
        const int col = nt * 128 + wn * 64 + ni * 16 + lr;
        y[(size_t)row * H_DIM + col] = f2bf(acc[mi][ni][r]);
      }
}

// ---------------- K6: combine (deterministic gather) -----------------------
__global__ __launch_bounds__(256) void k_combine(const unsigned short* __restrict__ y,
                                                 const int* __restrict__ topk_idx,
                                                 const float* __restrict__ topk_w,
                                                 const int* __restrict__ pair_pos,
                                                 const int* __restrict__ pstart,
                                                 float* __restrict__ out) {
  const int t = blockIdx.x;
  __shared__ int s_r[TOPK]; __shared__ float s_w[TOPK];
  if (threadIdx.x < TOPK) {
    const int e = topk_idx[t * TOPK + threadIdx.x];
    const int pos = pair_pos[t * TOPK + threadIdx.x];
    const int row = pstart[e] + pos;
    s_r[threadIdx.x] = (pos < CAPE && row < YROWS) ? row : -1;
    s_w[threadIdx.x] = topk_w[t * TOPK + threadIdx.x];
  }
  __syncthreads();
  const int h0 = threadIdx.x * 8;
  float acc[8] = {0.f, 0.f, 0.f, 0.f, 0.f, 0.f, 0.f, 0.f};
#pragma unroll
  for (int k = 0; k < TOPK; ++k) {
    const int row = s_r[k];
    if (row < 0) continue;
    const float w = s_w[k];
    const bf16x8 vv = *(const bf16x8*)(&y[(size_t)row * H_DIM + h0]);
#pragma unroll
    for (int j = 0; j < 8; ++j) acc[j] += w * bf2f((unsigned short)vv[j]);
  }
  float4 o0 = {acc[0], acc[1], acc[2], acc[3]};
  float4 o1 = {acc[4], acc[5], acc[6], acc[7]};
  *(float4*)(out + (size_t)t * H_DIM + h0)     = o0;
  *(float4*)(out + (size_t)t * H_DIM + h0 + 4) = o1;
}

// ---------------------------------------------------------------------------
extern "C" void kernel_launch(void* const* d_in, const int* in_sizes, int n_in,
                              void* d_out, int out_size, void* d_ws, size_t ws_size,
                              hipStream_t stream) {
  const float* x   = (const float*)d_in[0];
  const float* wr  = (const float*)d_in[1];
  const float* wgt = (const float*)d_in[2];
  const float* wup = (const float*)d_in[3];
  const float* wdn = (const float*)d_in[4];
  float* out = (float*)d_out;

  char* ws = (char*)d_ws;
  int*            topk_idx   = (int*)(ws);                    //  64 KiB
  float*          topk_w     = (float*)(ws + 65536);
  int*            pair_pos   = (int*)(ws + 131072);
  int*            cnts       = (int*)(ws + 196608);           // 256 B
  int*            pstart     = (int*)(ws + 196864);           // 260 B
  int*            slot_token = (int*)(ws + 197376);           // 128 KiB
  unsigned short* gbuf       = (unsigned short*)(ws + 524288);             // 48 MiB (becomes act)
  unsigned short* ubuf       = (unsigned short*)(ws + 524288 + 50331648);  // 48 MiB
  // y overlays ubuf (dead after k_act) and extends beyond: 96 MiB
  unsigned short* yb         = (unsigned short*)(ws + 524288 + 50331648);

  k_router <<<dim3(T_TOK / 4),         dim3(256), 0, stream>>>(x, wr, topk_idx, topk_w);
  k_rank   <<<dim3(1),                 dim3(256), 0, stream>>>(topk_idx, pair_pos, slot_token, cnts, pstart);
  k_mm1    <<<dim3(NEXP * MTMAX * 12), dim3(256), 0, stream>>>(x, wgt, wup, slot_token, cnts, gbuf, ubuf);
  k_act    <<<dim3(NEXP * 64),         dim3(256), 0, stream>>>(gbuf, ubuf, cnts);
  k_down   <<<dim3(NEXP * MTMAX * 16), dim3(256), 0, stream>>>(gbuf, wdn, cnts, pstart, yb);
  k_combine<<<dim3(T_TOK),             dim3(256), 0, stream>>>(yb, topk_idx, topk_w, pair_pos, pstart, out);
}